// Round 5
// baseline (198.097 us; speedup 1.0000x reference)
//
#include <hip/hip_runtime.h>

#define M_TOT 12544   // 64 images * 196 patches
#define HID   384
#define K_PE  768     // 3*16*16
#define NCOLS 75264   // 196*384 (p,c) columns

typedef unsigned short ushort_t;
using f32x4  = __attribute__((ext_vector_type(4))) float;
using short8 = __attribute__((ext_vector_type(8))) short;

// ---- bf16 helpers (RNE) ----------------------------------------------------
__device__ __forceinline__ unsigned short f2bf(float x) {
    union { float f; unsigned u; } v; v.f = x;
    return (unsigned short)((v.u + 0x7fffu + ((v.u >> 16) & 1u)) >> 16);
}
__device__ __forceinline__ unsigned bfpack(float lo, float hi) {
    union { float f; unsigned u; } a, b; a.f = lo; b.f = hi;
    unsigned ra = (a.u + 0x7fffu + ((a.u >> 16) & 1u)) >> 16;
    unsigned rb = (b.u + 0x7fffu + ((b.u >> 16) & 1u)) & 0xffff0000u;
    return ra | rb;
}
__device__ __forceinline__ float bflo(unsigned u) {
    union { unsigned u; float f; } v; v.u = u << 16; return v.f;
}
__device__ __forceinline__ float bfhi(unsigned u) {
    union { unsigned u; float f; } v; v.u = u & 0xffff0000u; return v.f;
}

// ---------------- prep: zero scal/Lsum/Qsum + convert W to bf16 -------------
// grid 148 x 256 = 37888 threads.
__global__ __launch_bounds__(256) void prep(const float* __restrict__ W,
                                            ushort_t* __restrict__ Wbf,
                                            float* __restrict__ scal,
                                            float* __restrict__ Lsum,
                                            float* __restrict__ Qsum) {
    int idx = blockIdx.x * 256 + threadIdx.x;
    if (idx < 4) scal[idx] = 0.f;
    if (idx < NCOLS / 4) {
        ((float4*)Lsum)[idx] = float4{0.f, 0.f, 0.f, 0.f};
        ((float4*)Qsum)[idx] = float4{0.f, 0.f, 0.f, 0.f};
    }
    if (idx < 36864) {
        const float4 a = *(const float4*)(W + (size_t)idx * 8);
        const float4 b = *(const float4*)(W + (size_t)idx * 8 + 4);
        uint4 p;
        p.x = bfpack(a.x, a.y); p.y = bfpack(a.z, a.w);
        p.z = bfpack(b.x, b.y); p.w = bfpack(b.z, b.w);
        ((uint4*)Wbf)[idx] = p;
    }
}

// ---------------- fused patch-embed GEMM + softmax --------------------------
// M-tile 32, full N=384, K=768 in 64-chunks. grid (392, 2) [y = x|e] = 784
// blocks. Block 256 = 4 waves; wave tile 32M x 96N (2x6 frags of 16x16x32).
// A: read once, fp32->bf16 fused, double-buffered 4 KB LDS (XOR-swizzled).
// B (bf16 W): direct global->register frag loads — each load is 16 full
// 64-B lines (lanes lm share col, lq*8 k-offsets are contiguous), L2-hot.
// Epilogue: row softmax on fp32 accs (16-lane butterfly + LDS combine).
__global__ __launch_bounds__(256, 3) void pe_softmax(
    const float* __restrict__ xin, const float* __restrict__ yin,
    const ushort_t* __restrict__ Wbf, const float* __restrict__ bias,
    ushort_t* __restrict__ xe, ushort_t* __restrict__ ye) {
    const float* im   = blockIdx.y ? yin : xin;
    ushort_t*    outp = blockIdx.y ? ye  : xe;
    const int mtile = blockIdx.x * 32;

    __shared__ __align__(16) ushort_t As[2][32 * 64];  // 2 x 4 KB
    __shared__ float Sm[4][32];
    __shared__ float Ss[4][32];

    const int tid  = threadIdx.x;
    const int wave = tid >> 6;
    const int lane = tid & 63;
    const int lm   = lane & 15;
    const int lq   = lane >> 4;
    const int wn   = wave * 96;

    // ---- A staging ids: thread -> (row sm, 8-elem k-octet qt)
    const int sm = tid >> 3;          // 0..31
    const int qt = tid & 7;           // 0..7
    int mg = mtile + sm;
    int pb = mg / 196;
    int pr = mg - pb * 196;
    int pi = pr / 14;
    int pj = pr - pi * 14;
    const float* aptr = im + ((size_t)(pb * 3) * 224 + pi * 16) * 224 + pj * 16;
    const int awoff = sm * 64 + ((qt ^ (sm & 7)) * 8);

    // ---- frag read offsets (k-step invariant)
    int ard[2][2];
#pragma unroll
    for (int ks = 0; ks < 2; ++ks)
#pragma unroll
        for (int mi = 0; mi < 2; ++mi)
            ard[ks][mi] = (mi * 16 + lm) * 64 + (((ks * 4 + lq) ^ (lm & 7)) * 8);

    // ---- B lane base: col = wn + ni*16 + lm, k-offset lq*8
    const ushort_t* bbase = Wbf + (size_t)(wn + lm) * K_PE + lq * 8;

    f32x4 acc[2][6] = {};

#define STAGE_A(KB, BUF)                                                     \
    {                                                                        \
        const int k0 = (KB) + qt * 8;                                        \
        const int c  = k0 >> 8;                                              \
        const int di = (k0 >> 4) & 15;                                       \
        const int dj = k0 & 15;                                              \
        const float* ap = aptr + (c * 224 + di) * 224 + dj;                  \
        float4 f0 = *(const float4*)(ap);                                    \
        float4 f1 = *(const float4*)(ap + 4);                                \
        uint4 p;                                                             \
        p.x = bfpack(f0.x, f0.y); p.y = bfpack(f0.z, f0.w);                  \
        p.z = bfpack(f1.x, f1.y); p.w = bfpack(f1.z, f1.w);                  \
        *(uint4*)&As[BUF][awoff] = p;                                        \
    }

    STAGE_A(0, 0)
    __syncthreads();

    for (int kbi = 0; kbi < 12; ++kbi) {
        const int kb  = kbi * 64;
        const int cur = kbi & 1;
        if (kbi < 11) STAGE_A(kb + 64, cur ^ 1)
#pragma unroll
        for (int ks = 0; ks < 2; ++ks) {
            short8 af[2], bfr[6];
#pragma unroll
            for (int ni = 0; ni < 6; ++ni)
                bfr[ni] = *(const short8*)(bbase + ni * 16 * K_PE + kb + ks * 32);
#pragma unroll
            for (int mi = 0; mi < 2; ++mi)
                af[mi] = *(const short8*)&As[cur][ard[ks][mi]];
#pragma unroll
            for (int mi = 0; mi < 2; ++mi)
#pragma unroll
                for (int ni = 0; ni < 6; ++ni)
                    acc[mi][ni] = __builtin_amdgcn_mfma_f32_16x16x32_bf16(
                        af[mi], bfr[ni], acc[mi][ni], 0, 0, 0);
        }
        __syncthreads();
    }
#undef STAGE_A

    // ---- epilogue: bias + row softmax + store -------------------------------
    // D frag layout: col = wn + ni*16 + lm, row = mi*16 + lq*4 + reg.
#pragma unroll
    for (int ni = 0; ni < 6; ++ni) {
        const float bv = bias[wn + ni * 16 + lm];
#pragma unroll
        for (int mi = 0; mi < 2; ++mi)
#pragma unroll
            for (int r = 0; r < 4; ++r)
                acc[mi][ni][r] += bv;
    }

    // pass 1: row max over this wave's 96 cols, butterfly within 16-lane group
    float mrow[2][4];
#pragma unroll
    for (int mi = 0; mi < 2; ++mi)
#pragma unroll
        for (int r = 0; r < 4; ++r) {
            float m = acc[mi][0][r];
#pragma unroll
            for (int ni = 1; ni < 6; ++ni) m = fmaxf(m, acc[mi][ni][r]);
            mrow[mi][r] = m;
        }
#pragma unroll
    for (int off = 1; off < 16; off <<= 1)
#pragma unroll
        for (int mi = 0; mi < 2; ++mi)
#pragma unroll
            for (int r = 0; r < 4; ++r)
                mrow[mi][r] = fmaxf(mrow[mi][r], __shfl_xor(mrow[mi][r], off));
    if (lm == 0)
#pragma unroll
        for (int mi = 0; mi < 2; ++mi)
#pragma unroll
            for (int r = 0; r < 4; ++r)
                Sm[wave][mi * 16 + lq * 4 + r] = mrow[mi][r];
    __syncthreads();
#pragma unroll
    for (int mi = 0; mi < 2; ++mi)
#pragma unroll
        for (int r = 0; r < 4; ++r) {
            const int row = mi * 16 + lq * 4 + r;
            mrow[mi][r] = fmaxf(fmaxf(Sm[0][row], Sm[1][row]),
                                fmaxf(Sm[2][row], Sm[3][row]));
        }

    // pass 2: row sum of exp
    float srow[2][4];
#pragma unroll
    for (int mi = 0; mi < 2; ++mi)
#pragma unroll
        for (int r = 0; r < 4; ++r) {
            float s = 0.f;
#pragma unroll
            for (int ni = 0; ni < 6; ++ni) s += __expf(acc[mi][ni][r] - mrow[mi][r]);
            srow[mi][r] = s;
        }
#pragma unroll
    for (int off = 1; off < 16; off <<= 1)
#pragma unroll
        for (int mi = 0; mi < 2; ++mi)
#pragma unroll
            for (int r = 0; r < 4; ++r)
                srow[mi][r] += __shfl_xor(srow[mi][r], off);
    if (lm == 0)
#pragma unroll
        for (int mi = 0; mi < 2; ++mi)
#pragma unroll
            for (int r = 0; r < 4; ++r)
                Ss[wave][mi * 16 + lq * 4 + r] = srow[mi][r];
    __syncthreads();
#pragma unroll
    for (int mi = 0; mi < 2; ++mi)
#pragma unroll
        for (int r = 0; r < 4; ++r) {
            const int row = mi * 16 + lq * 4 + r;
            srow[mi][r] = Ss[0][row] + Ss[1][row] + Ss[2][row] + Ss[3][row];
        }

    // pass 3: store logp (x) or q (y) as bf16
    if (blockIdx.y == 0) {
#pragma unroll
        for (int mi = 0; mi < 2; ++mi)
#pragma unroll
            for (int r = 0; r < 4; ++r) {
                const float sh = mrow[mi][r] + __logf(srow[mi][r]);
                const size_t grow = mtile + mi * 16 + lq * 4 + r;
#pragma unroll
                for (int ni = 0; ni < 6; ++ni)
                    outp[grow * HID + wn + ni * 16 + lm] = f2bf(acc[mi][ni][r] - sh);
            }
    } else {
#pragma unroll
        for (int mi = 0; mi < 2; ++mi)
#pragma unroll
            for (int r = 0; r < 4; ++r) {
                const float m   = mrow[mi][r];
                const float inv = 1.f / srow[mi][r];
                const size_t grow = mtile + mi * 16 + lq * 4 + r;
#pragma unroll
                for (int ni = 0; ni < 6; ++ni)
                    outp[grow * HID + wn + ni * 16 + lm] =
                        f2bf(__expf(acc[mi][ni][r] - m) * inv);
            }
    }
}

// ---------------- pass 1 of reduce: T + per-column sums ---------------------
// T = sum elementwise logp*q (image-split OK). Column sums over images go
// to Lsum/Qsum[75264] via atomics (4-way contention per address).
// grid 147 x 256 = 37632 threads = 9408 col-groups x 4 image-splits.
__global__ __launch_bounds__(256) void colsum_t(const ushort_t* __restrict__ logp,
                                                const ushort_t* __restrict__ q,
                                                float* __restrict__ Lsum,
                                                float* __restrict__ Qsum,
                                                float* __restrict__ scal) {
    const int t  = blockIdx.x * 256 + threadIdx.x;
    const int cg = t % 9408;
    const int ig = t / 9408;          // 0..3
    const int col = cg * 8;
    float Ls[8] = {}, Qs[8] = {}, T = 0.f;
    for (int ii = 0; ii < 16; ++ii) {
        const int i = ig * 16 + ii;
        const size_t base = (size_t)i * NCOLS + col;
        uint4 lp = *(const uint4*)(logp + base);
        uint4 qp = *(const uint4*)(q + base);
        float l[8], qq[8];
        l[0] = bflo(lp.x); l[1] = bfhi(lp.x); l[2] = bflo(lp.y); l[3] = bfhi(lp.y);
        l[4] = bflo(lp.z); l[5] = bfhi(lp.z); l[6] = bflo(lp.w); l[7] = bfhi(lp.w);
        qq[0] = bflo(qp.x); qq[1] = bfhi(qp.x); qq[2] = bflo(qp.y); qq[3] = bfhi(qp.y);
        qq[4] = bflo(qp.z); qq[5] = bfhi(qp.z); qq[6] = bflo(qp.w); qq[7] = bfhi(qp.w);
#pragma unroll
        for (int j = 0; j < 8; ++j) {
            T += l[j] * qq[j];
            Ls[j] += l[j];
            Qs[j] += qq[j];
        }
    }
#pragma unroll
    for (int j = 0; j < 8; ++j) {
        atomicAdd(&Lsum[col + j], Ls[j]);
        atomicAdd(&Qsum[col + j], Qs[j]);
    }
    // block reduce T -> one atomic
#pragma unroll
    for (int off = 32; off > 0; off >>= 1) T += __shfl_xor(T, off);
    __shared__ float sT[4];
    if ((threadIdx.x & 63) == 0) sT[threadIdx.x >> 6] = T;
    __syncthreads();
    if (threadIdx.x == 0)
        atomicAdd(&scal[0], sT[0] + sT[1] + sT[2] + sT[3]);
}

// ---------------- pass 2: S = dot(Lsum, Qsum) -------------------------------
// grid 37 x 256 = 9472 threads over 18816 float4 groups.
__global__ __launch_bounds__(256) void final_dot(const float* __restrict__ Lsum,
                                                 const float* __restrict__ Qsum,
                                                 float* __restrict__ scal) {
    float s = 0.f;
    for (int idx = blockIdx.x * 256 + threadIdx.x; idx < NCOLS / 4; idx += 9472) {
        float4 a = ((const float4*)Lsum)[idx];
        float4 b = ((const float4*)Qsum)[idx];
        s += a.x * b.x + a.y * b.y + a.z * b.z + a.w * b.w;
    }
#pragma unroll
    for (int off = 32; off > 0; off >>= 1) s += __shfl_xor(s, off);
    __shared__ float sS[4];
    if ((threadIdx.x & 63) == 0) sS[threadIdx.x >> 6] = s;
    __syncthreads();
    if (threadIdx.x == 0)
        atomicAdd(&scal[1], sS[0] + sS[1] + sS[2] + sS[3]);
}

// ---------------- final scalar ----------------------------------------------
// close/far = (T/64) / ((S-T)/4032) = 63*T/(S-T); -1/196 factors cancel.
__global__ void final_k(const float* __restrict__ scal, float* __restrict__ out) {
    if (threadIdx.x == 0) {
        float T = scal[0], S = scal[1];
        out[0] = 63.f * T / (S - T);
    }
}

extern "C" void kernel_launch(void* const* d_in, const int* in_sizes, int n_in,
                              void* d_out, int out_size, void* d_ws, size_t ws_size,
                              hipStream_t stream) {
    const float* x = (const float*)d_in[0];   // (64,3,224,224)
    const float* y = (const float*)d_in[1];   // (64,3,224,224)
    const float* W = (const float*)d_in[2];   // (384,768)
    const float* b = (const float*)d_in[3];   // (384,)
    float* out = (float*)d_out;

    float*    scal = (float*)d_ws;                       // 16 f32 (T, S, pad)
    float*    Lsum = scal + 16;                          // 75264 f32
    float*    Qsum = Lsum + NCOLS;                       // 75264 f32
    ushort_t* Wbf  = (ushort_t*)(Qsum + NCOLS);          // 294912 bf16
    ushort_t* xe   = Wbf + 294912;                       // 12544*384 bf16 (logp)
    ushort_t* ye   = xe + (size_t)M_TOT * HID;           // 12544*384 bf16 (q)

    prep<<<148, 256, 0, stream>>>(W, Wbf, scal, Lsum, Qsum);
    pe_softmax<<<dim3(392, 2), 256, 0, stream>>>(x, y, Wbf, b, xe, ye);
    colsum_t<<<147, 256, 0, stream>>>(xe, ye, Lsum, Qsum, scal);
    final_dot<<<37, 256, 0, stream>>>(Lsum, Qsum, scal);
    final_k<<<1, 64, 0, stream>>>(scal, out);
}

// Round 6
// 180.833 us; speedup vs baseline: 1.0955x; 1.0955x over previous
//
#include <hip/hip_runtime.h>

#define M_TOT 12544   // 64 images * 196 patches
#define HID   384
#define K_PE  768     // 3*16*16
#define NCOLS 75264   // 196*384 (p,c) columns

typedef unsigned short ushort_t;
using f32x4  = __attribute__((ext_vector_type(4))) float;
using short8 = __attribute__((ext_vector_type(8))) short;

// ---- bf16 helpers (RNE) ----------------------------------------------------
__device__ __forceinline__ unsigned short f2bf(float x) {
    union { float f; unsigned u; } v; v.f = x;
    return (unsigned short)((v.u + 0x7fffu + ((v.u >> 16) & 1u)) >> 16);
}
__device__ __forceinline__ unsigned bfpack(float lo, float hi) {
    union { float f; unsigned u; } a, b; a.f = lo; b.f = hi;
    unsigned ra = (a.u + 0x7fffu + ((a.u >> 16) & 1u)) >> 16;
    unsigned rb = (b.u + 0x7fffu + ((b.u >> 16) & 1u)) & 0xffff0000u;
    return ra | rb;
}
__device__ __forceinline__ float bflo(unsigned u) {
    union { unsigned u; float f; } v; v.u = u << 16; return v.f;
}
__device__ __forceinline__ float bfhi(unsigned u) {
    union { unsigned u; float f; } v; v.u = u & 0xffff0000u; return v.f;
}

// ---------------- prep: zero accumulators + swizzle W into B-frag order -----
// Wfrag layout: [nt(24)][kc(24)][lane(64)][8] bf16, where for mfma_16x16x32
// B-frag: n = nt*16 + (lane&15), k = kc*32 + (lane>>4)*8 + j. A wave's frag
// load is then ONE contiguous 1 KB segment (no 16-way line split).
// grid 144 x 256 = 36864 threads = 384 rows x 96 k-octets.
__global__ __launch_bounds__(256) void prep(const float* __restrict__ W,
                                            ushort_t* __restrict__ Wfrag,
                                            float* __restrict__ scal,
                                            float* __restrict__ Lsum,
                                            float* __restrict__ Qsum) {
    const int t = blockIdx.x * 256 + threadIdx.x;
    if (t < 4) scal[t] = 0.f;                       // T, S, pad, done-counter
    if (t < NCOLS / 4) {
        ((float4*)Lsum)[t] = float4{0.f, 0.f, 0.f, 0.f};
        ((float4*)Qsum)[t] = float4{0.f, 0.f, 0.f, 0.f};
    }
    const int n  = t / 96;          // 0..383
    const int ko = t % 96;          // k-octet
    const float4 a = *(const float4*)(W + (size_t)n * K_PE + ko * 8);
    const float4 b = *(const float4*)(W + (size_t)n * K_PE + ko * 8 + 4);
    uint4 p;
    p.x = bfpack(a.x, a.y); p.y = bfpack(a.z, a.w);
    p.z = bfpack(b.x, b.y); p.w = bfpack(b.z, b.w);
    const int nt   = n >> 4;
    const int kc   = ko >> 2;
    const int lane = (ko & 3) * 16 + (n & 15);
    ((uint4*)Wfrag)[(nt * 24 + kc) * 64 + lane] = p;
}

// ---------------- fused patch-embed GEMM + softmax --------------------------
// M-tile 64, full N=384, K=768 in 64-chunks. grid (196, 2) [y = x|e] = 392
// blocks of 512 = 8 waves (2 m-halves x 4 n-waves); wave tile 32M x 96N.
// A: read once, fp32->bf16 fused, double-buffered 8 KB LDS (XOR-swizzled).
// B: direct global->register from Wfrag — each frag load is one coalesced
// 1 KB wave segment, L2-resident. Epilogue: fused row softmax.
__global__ __launch_bounds__(512, 4) void pe_softmax(
    const float* __restrict__ xin, const float* __restrict__ yin,
    const ushort_t* __restrict__ Wfrag, const float* __restrict__ bias,
    ushort_t* __restrict__ xe, ushort_t* __restrict__ ye) {
    const float* im   = blockIdx.y ? yin : xin;
    ushort_t*    outp = blockIdx.y ? ye  : xe;
    const int mtile = blockIdx.x * 64;

    __shared__ __align__(16) ushort_t As[2][64 * 64];  // 2 x 8 KB
    __shared__ float Sm[8][32];
    __shared__ float Ss[8][32];

    const int tid  = threadIdx.x;
    const int wave = tid >> 6;
    const int lane = tid & 63;
    const int lm   = lane & 15;
    const int lq   = lane >> 4;
    const int mg   = wave >> 2;       // m-half 0/1
    const int nw   = wave & 3;        // n-wave
    const int wn   = nw * 96;

    // ---- A staging ids: thread -> (row sm, 8-elem k-octet qt)
    const int sm = tid >> 3;          // 0..63
    const int qt = tid & 7;           // 0..7
    int mgl = mtile + sm;
    int pb = mgl / 196;
    int pr = mgl - pb * 196;
    int pi = pr / 14;
    int pj = pr - pi * 14;
    const float* aptr = im + ((size_t)(pb * 3) * 224 + pi * 16) * 224 + pj * 16;
    const int awoff = sm * 64 + ((qt ^ (sm & 7)) * 8);

    // ---- frag read offsets (k-step invariant)
    int ard[2][2];
#pragma unroll
    for (int ks = 0; ks < 2; ++ks)
#pragma unroll
        for (int mi = 0; mi < 2; ++mi)
            ard[ks][mi] = (mg * 32 + mi * 16 + lm) * 64 + (((ks * 4 + lq) ^ (lm & 7)) * 8);

    // ---- B frag base: nt = nw*6 + ni, kc = kbi*2 + ks
    const ushort_t* bbase = Wfrag + (size_t)lane * 8;

    f32x4 acc[2][6] = {};

#define STAGE_A(KB, BUF)                                                     \
    {                                                                        \
        const int k0 = (KB) + qt * 8;                                        \
        const int c  = k0 >> 8;                                              \
        const int di = (k0 >> 4) & 15;                                       \
        const int dj = k0 & 15;                                              \
        const float* ap = aptr + (c * 224 + di) * 224 + dj;                  \
        float4 f0 = *(const float4*)(ap);                                    \
        float4 f1 = *(const float4*)(ap + 4);                                \
        uint4 p;                                                             \
        p.x = bfpack(f0.x, f0.y); p.y = bfpack(f0.z, f0.w);                  \
        p.z = bfpack(f1.x, f1.y); p.w = bfpack(f1.z, f1.w);                  \
        *(uint4*)&As[BUF][awoff] = p;                                        \
    }

    STAGE_A(0, 0)
    __syncthreads();

    for (int kbi = 0; kbi < 12; ++kbi) {
        const int cur = kbi & 1;
        if (kbi < 11) STAGE_A(kbi * 64 + 64, cur ^ 1)
#pragma unroll
        for (int ks = 0; ks < 2; ++ks) {
            short8 af[2], bfr[6];
#pragma unroll
            for (int ni = 0; ni < 6; ++ni)
                bfr[ni] = *(const short8*)(bbase +
                          (size_t)(((nw * 6 + ni) * 24 + kbi * 2 + ks) * 64) * 8);
#pragma unroll
            for (int mi = 0; mi < 2; ++mi)
                af[mi] = *(const short8*)&As[cur][ard[ks][mi]];
#pragma unroll
            for (int mi = 0; mi < 2; ++mi)
#pragma unroll
                for (int ni = 0; ni < 6; ++ni)
                    acc[mi][ni] = __builtin_amdgcn_mfma_f32_16x16x32_bf16(
                        af[mi], bfr[ni], acc[mi][ni], 0, 0, 0);
        }
        __syncthreads();
    }
#undef STAGE_A

    // ---- epilogue: bias + row softmax + store -------------------------------
    // D frag: col = wn + ni*16 + lm, row(local) = mi*16 + lq*4 + r (within m-half)
#pragma unroll
    for (int ni = 0; ni < 6; ++ni) {
        const float bv = bias[wn + ni * 16 + lm];
#pragma unroll
        for (int mi = 0; mi < 2; ++mi)
#pragma unroll
            for (int r = 0; r < 4; ++r)
                acc[mi][ni][r] += bv;
    }

    float mrow[2][4];
#pragma unroll
    for (int mi = 0; mi < 2; ++mi)
#pragma unroll
        for (int r = 0; r < 4; ++r) {
            float m = acc[mi][0][r];
#pragma unroll
            for (int ni = 1; ni < 6; ++ni) m = fmaxf(m, acc[mi][ni][r]);
            mrow[mi][r] = m;
        }
#pragma unroll
    for (int off = 1; off < 16; off <<= 1)
#pragma unroll
        for (int mi = 0; mi < 2; ++mi)
#pragma unroll
            for (int r = 0; r < 4; ++r)
                mrow[mi][r] = fmaxf(mrow[mi][r], __shfl_xor(mrow[mi][r], off));
    if (lm == 0)
#pragma unroll
        for (int mi = 0; mi < 2; ++mi)
#pragma unroll
            for (int r = 0; r < 4; ++r)
                Sm[wave][mi * 16 + lq * 4 + r] = mrow[mi][r];
    __syncthreads();
#pragma unroll
    for (int mi = 0; mi < 2; ++mi)
#pragma unroll
        for (int r = 0; r < 4; ++r) {
            const int row = mi * 16 + lq * 4 + r;
            mrow[mi][r] = fmaxf(fmaxf(Sm[mg * 4 + 0][row], Sm[mg * 4 + 1][row]),
                                fmaxf(Sm[mg * 4 + 2][row], Sm[mg * 4 + 3][row]));
        }

    float srow[2][4];
#pragma unroll
    for (int mi = 0; mi < 2; ++mi)
#pragma unroll
        for (int r = 0; r < 4; ++r) {
            float s = 0.f;
#pragma unroll
            for (int ni = 0; ni < 6; ++ni) s += __expf(acc[mi][ni][r] - mrow[mi][r]);
            srow[mi][r] = s;
        }
#pragma unroll
    for (int off = 1; off < 16; off <<= 1)
#pragma unroll
        for (int mi = 0; mi < 2; ++mi)
#pragma unroll
            for (int r = 0; r < 4; ++r)
                srow[mi][r] += __shfl_xor(srow[mi][r], off);
    if (lm == 0)
#pragma unroll
        for (int mi = 0; mi < 2; ++mi)
#pragma unroll
            for (int r = 0; r < 4; ++r)
                Ss[wave][mi * 16 + lq * 4 + r] = srow[mi][r];
    __syncthreads();
#pragma unroll
    for (int mi = 0; mi < 2; ++mi)
#pragma unroll
        for (int r = 0; r < 4; ++r) {
            const int row = mi * 16 + lq * 4 + r;
            srow[mi][r] = Ss[mg * 4 + 0][row] + Ss[mg * 4 + 1][row] +
                          Ss[mg * 4 + 2][row] + Ss[mg * 4 + 3][row];
        }

    if (blockIdx.y == 0) {
#pragma unroll
        for (int mi = 0; mi < 2; ++mi)
#pragma unroll
            for (int r = 0; r < 4; ++r) {
                const float sh = mrow[mi][r] + __logf(srow[mi][r]);
                const size_t grow = mtile + mg * 32 + mi * 16 + lq * 4 + r;
#pragma unroll
                for (int ni = 0; ni < 6; ++ni)
                    outp[grow * HID + wn + ni * 16 + lm] = f2bf(acc[mi][ni][r] - sh);
            }
    } else {
#pragma unroll
        for (int mi = 0; mi < 2; ++mi)
#pragma unroll
            for (int r = 0; r < 4; ++r) {
                const float m   = mrow[mi][r];
                const float inv = 1.f / srow[mi][r];
                const size_t grow = mtile + mg * 32 + mi * 16 + lq * 4 + r;
#pragma unroll
                for (int ni = 0; ni < 6; ++ni)
                    outp[grow * HID + wn + ni * 16 + lm] =
                        f2bf(__expf(acc[mi][ni][r] - m) * inv);
            }
    }
}

// ---------------- reduce pass 1: T + per-column sums ------------------------
// grid 294 x 256 = 75264 threads = 9408 col-groups x 8 image-splits.
__global__ __launch_bounds__(256) void colsum_t(const ushort_t* __restrict__ logp,
                                                const ushort_t* __restrict__ q,
                                                float* __restrict__ Lsum,
                                                float* __restrict__ Qsum,
                                                float* __restrict__ scal) {
    const int t  = blockIdx.x * 256 + threadIdx.x;
    const int cg = t % 9408;
    const int ig = t / 9408;          // 0..7
    const int col = cg * 8;
    float Ls[8] = {}, Qs[8] = {}, T = 0.f;
    for (int ii = 0; ii < 8; ++ii) {
        const int i = ig * 8 + ii;
        const size_t base = (size_t)i * NCOLS + col;
        uint4 lp = *(const uint4*)(logp + base);
        uint4 qp = *(const uint4*)(q + base);
        float l[8], qq[8];
        l[0] = bflo(lp.x); l[1] = bfhi(lp.x); l[2] = bflo(lp.y); l[3] = bfhi(lp.y);
        l[4] = bflo(lp.z); l[5] = bfhi(lp.z); l[6] = bflo(lp.w); l[7] = bfhi(lp.w);
        qq[0] = bflo(qp.x); qq[1] = bfhi(qp.x); qq[2] = bflo(qp.y); qq[3] = bfhi(qp.y);
        qq[4] = bflo(qp.z); qq[5] = bfhi(qp.z); qq[6] = bflo(qp.w); qq[7] = bfhi(qp.w);
#pragma unroll
        for (int j = 0; j < 8; ++j) {
            T += l[j] * qq[j];
            Ls[j] += l[j];
            Qs[j] += qq[j];
        }
    }
#pragma unroll
    for (int j = 0; j < 8; ++j) {
        atomicAdd(&Lsum[col + j], Ls[j]);
        atomicAdd(&Qsum[col + j], Qs[j]);
    }
#pragma unroll
    for (int off = 32; off > 0; off >>= 1) T += __shfl_xor(T, off);
    __shared__ float sT[4];
    if ((threadIdx.x & 63) == 0) sT[threadIdx.x >> 6] = T;
    __syncthreads();
    if (threadIdx.x == 0)
        atomicAdd(&scal[0], sT[0] + sT[1] + sT[2] + sT[3]);
}

// ---------------- reduce pass 2: S = dot(Lsum,Qsum) + finalize --------------
// grid 74 x 256; one float4 pair per thread. Last-done block computes the
// final ratio (S read back atomically — coherent across XCDs).
__global__ __launch_bounds__(256) void final_dot(const float* __restrict__ Lsum,
                                                 const float* __restrict__ Qsum,
                                                 float* __restrict__ scal,
                                                 float* __restrict__ out) {
    const int idx = blockIdx.x * 256 + threadIdx.x;
    float s = 0.f;
    if (idx < NCOLS / 4) {
        float4 a = ((const float4*)Lsum)[idx];
        float4 b = ((const float4*)Qsum)[idx];
        s = a.x * b.x + a.y * b.y + a.z * b.z + a.w * b.w;
    }
#pragma unroll
    for (int off = 32; off > 0; off >>= 1) s += __shfl_xor(s, off);
    __shared__ float sS[4];
    __shared__ int lastflag;
    if ((threadIdx.x & 63) == 0) sS[threadIdx.x >> 6] = s;
    __syncthreads();
    if (threadIdx.x == 0) {
        atomicAdd(&scal[1], sS[0] + sS[1] + sS[2] + sS[3]);
        __threadfence();
        int old = atomicAdd((int*)&scal[3], 1);
        lastflag = (old == (int)gridDim.x - 1);
    }
    __syncthreads();
    if (lastflag && threadIdx.x == 0) {
        float S = atomicAdd(&scal[1], 0.f);   // coherent read of final sum
        float T = atomicAdd(&scal[0], 0.f);
        out[0] = 63.f * T / (S - T);
    }
}

extern "C" void kernel_launch(void* const* d_in, const int* in_sizes, int n_in,
                              void* d_out, int out_size, void* d_ws, size_t ws_size,
                              hipStream_t stream) {
    const float* x = (const float*)d_in[0];   // (64,3,224,224)
    const float* y = (const float*)d_in[1];   // (64,3,224,224)
    const float* W = (const float*)d_in[2];   // (384,768)
    const float* b = (const float*)d_in[3];   // (384,)
    float* out = (float*)d_out;

    float*    scal  = (float*)d_ws;                      // 16 f32: T,S,pad,cnt
    float*    Lsum  = scal + 16;                         // 75264 f32
    float*    Qsum  = Lsum + NCOLS;                      // 75264 f32
    ushort_t* Wfrag = (ushort_t*)(Qsum + NCOLS);         // 294912 bf16
    ushort_t* xe    = Wfrag + 294912;                    // 12544*384 bf16 (logp)
    ushort_t* ye    = xe + (size_t)M_TOT * HID;          // 12544*384 bf16 (q)

    prep<<<144, 256, 0, stream>>>(W, Wfrag, scal, Lsum, Qsum);
    pe_softmax<<<dim3(196, 2), 512, 0, stream>>>(x, y, Wfrag, b, xe, ye);
    colsum_t<<<294, 256, 0, stream>>>(xe, ye, Lsum, Qsum, scal);
    final_dot<<<74, 256, 0, stream>>>(Lsum, Qsum, scal, out);
}

// Round 7
// 145.612 us; speedup vs baseline: 1.3604x; 1.2419x over previous
//
#include <hip/hip_runtime.h>

#define HID   384
#define K_PE  768     // 3*16*16
#define IMGST 150528  // 3*224*224 floats per image

typedef unsigned short ushort_t;
using f32x4  = __attribute__((ext_vector_type(4))) float;
using short8 = __attribute__((ext_vector_type(8))) short;

// ---- bf16 helpers (RNE) ----------------------------------------------------
__device__ __forceinline__ unsigned bfpack(float lo, float hi) {
    union { float f; unsigned u; } a, b; a.f = lo; b.f = hi;
    unsigned ra = (a.u + 0x7fffu + ((a.u >> 16) & 1u)) >> 16;
    unsigned rb = (b.u + 0x7fffu + ((b.u >> 16) & 1u)) & 0xffff0000u;
    return ra | rb;
}

// ---------------- prep: zero scalars + swizzle W into B-frag order ----------
// Wfrag: [nt(24)][kc(24)][lane(64)][8] bf16; B-frag n = nt*16 + (lane&15),
// k = kc*32 + (lane>>4)*8 + j -> one frag load = one contiguous 1 KB segment.
// grid 144 x 256 = 36864 threads = 384 rows x 96 k-octets.
__global__ __launch_bounds__(256) void prep(const float* __restrict__ W,
                                            ushort_t* __restrict__ Wfrag,
                                            float* __restrict__ scal) {
    const int t = blockIdx.x * 256 + threadIdx.x;
    if (t < 4) scal[t] = 0.f;                  // T, S, pad, done-counter
    const int n  = t / 96;                     // 0..383
    const int ko = t % 96;                     // k-octet
    const float4 a = *(const float4*)(W + (size_t)n * K_PE + ko * 8);
    const float4 b = *(const float4*)(W + (size_t)n * K_PE + ko * 8 + 4);
    uint4 p;
    p.x = bfpack(a.x, a.y); p.y = bfpack(a.z, a.w);
    p.z = bfpack(b.x, b.y); p.w = bfpack(b.z, b.w);
    const int nt   = n >> 4;
    const int kc   = ko >> 2;
    const int lane = (ko & 3) * 16 + (n & 15);
    ((uint4*)Wfrag)[(nt * 24 + kc) * 64 + lane] = p;
}

// ---------------- fully fused kernel ----------------------------------------
// grid 196 (one block per patch position p), block 512 = 8 waves.
// M = 64 images at position p; N = 384; K = 768. Both x and y GEMMs in one
// block (B-frags shared). Epilogue: fused softmax (fp32), then
//   T_p  = sum_{i,c} logp[i,c] * q[i,c]
//   L[c] = sum_i logp[i,c],  Q[c] = sum_i q[i,c],  S_p = sum_c L[c]*Q[c]
// atomicAdd T_p, S_p; last block writes out = 63*T/(S-T).
__global__ __launch_bounds__(512, 2) void pe_all(
    const float* __restrict__ xin, const float* __restrict__ yin,
    const ushort_t* __restrict__ Wfrag, const float* __restrict__ bias,
    float* __restrict__ scal, float* __restrict__ out) {
    const int p  = blockIdx.x;
    const int pi = p / 14;
    const int pj = p - pi * 14;

    __shared__ __align__(16) ushort_t Asx[2][64 * 64];  // 2 x 8 KB
    __shared__ __align__(16) ushort_t Asy[2][64 * 64];  // 2 x 8 KB
    __shared__ float Smx[8][32], Ssx[8][32], Smy[8][32], Ssy[8][32];
    __shared__ float LcL[2][HID], LcQ[2][HID];
    __shared__ float sT[8], sS[8];

    const int tid  = threadIdx.x;
    const int wave = tid >> 6;
    const int lane = tid & 63;
    const int lm   = lane & 15;
    const int lq   = lane >> 4;
    const int mg   = wave >> 2;       // m-half (images 0-31 / 32-63)
    const int nw   = wave & 3;        // n-wave (96 cols)
    const int wn   = nw * 96;

    // ---- A staging ids: row sm = image, k-octet qt
    const int sm = tid >> 3;          // 0..63
    const int qt = tid & 7;           // 0..7
    const float* abx = xin + (size_t)sm * IMGST + pi * 3584 + pj * 16;
    const float* aby = yin + (size_t)sm * IMGST + pi * 3584 + pj * 16;
    const int awoff = sm * 64 + ((qt ^ (sm & 7)) * 8);

    // ---- frag read offsets (k-step invariant)
    int ard[2][2];
#pragma unroll
    for (int ks = 0; ks < 2; ++ks)
#pragma unroll
        for (int mi = 0; mi < 2; ++mi)
            ard[ks][mi] = (mg * 32 + mi * 16 + lm) * 64 +
                          (((ks * 4 + lq) ^ (lm & 7)) * 8);

    const ushort_t* bbase = Wfrag + (size_t)lane * 8;

    f32x4 accx[2][6] = {};
    f32x4 accy[2][6] = {};

#define STAGE(KB, BUF)                                                       \
    {                                                                        \
        const int k0  = (KB) + qt * 8;                                       \
        const int off = (k0 >> 8) * 50176 + (((k0 >> 4) & 15) * 224) + (k0 & 15); \
        float4 f0 = *(const float4*)(abx + off);                             \
        float4 f1 = *(const float4*)(abx + off + 4);                         \
        float4 g0 = *(const float4*)(aby + off);                             \
        float4 g1 = *(const float4*)(aby + off + 4);                         \
        uint4 px, py;                                                        \
        px.x = bfpack(f0.x, f0.y); px.y = bfpack(f0.z, f0.w);                \
        px.z = bfpack(f1.x, f1.y); px.w = bfpack(f1.z, f1.w);                \
        py.x = bfpack(g0.x, g0.y); py.y = bfpack(g0.z, g0.w);                \
        py.z = bfpack(g1.x, g1.y); py.w = bfpack(g1.z, g1.w);                \
        *(uint4*)&Asx[BUF][awoff] = px;                                      \
        *(uint4*)&Asy[BUF][awoff] = py;                                      \
    }

    STAGE(0, 0)
    __syncthreads();

    for (int kbi = 0; kbi < 12; ++kbi) {
        const int cur = kbi & 1;
        if (kbi < 11) STAGE(kbi * 64 + 64, cur ^ 1)
#pragma unroll
        for (int ks = 0; ks < 2; ++ks) {
            short8 bfr[6], afx[2], afy[2];
#pragma unroll
            for (int ni = 0; ni < 6; ++ni)
                bfr[ni] = *(const short8*)(bbase +
                          (size_t)(((nw * 6 + ni) * 24 + kbi * 2 + ks) * 64) * 8);
#pragma unroll
            for (int mi = 0; mi < 2; ++mi) {
                afx[mi] = *(const short8*)&Asx[cur][ard[ks][mi]];
                afy[mi] = *(const short8*)&Asy[cur][ard[ks][mi]];
            }
#pragma unroll
            for (int mi = 0; mi < 2; ++mi)
#pragma unroll
                for (int ni = 0; ni < 6; ++ni) {
                    accx[mi][ni] = __builtin_amdgcn_mfma_f32_16x16x32_bf16(
                        afx[mi], bfr[ni], accx[mi][ni], 0, 0, 0);
                    accy[mi][ni] = __builtin_amdgcn_mfma_f32_16x16x32_bf16(
                        afy[mi], bfr[ni], accy[mi][ni], 0, 0, 0);
                }
        }
        __syncthreads();
    }
#undef STAGE

    // ---- epilogue ----------------------------------------------------------
    // D frag: col = wn + ni*16 + lm; row(img) = mg*32 + mi*16 + lq*4 + r.
#pragma unroll
    for (int ni = 0; ni < 6; ++ni) {
        const float bv = bias[wn + ni * 16 + lm];
#pragma unroll
        for (int mi = 0; mi < 2; ++mi)
#pragma unroll
            for (int r = 0; r < 4; ++r) {
                accx[mi][ni][r] += bv;
                accy[mi][ni][r] += bv;
            }
    }

    // row max (x and y), butterfly over the 16-lane lm group
    float mx[2][4], my_[2][4];
#pragma unroll
    for (int mi = 0; mi < 2; ++mi)
#pragma unroll
        for (int r = 0; r < 4; ++r) {
            float a = accx[mi][0][r], b = accy[mi][0][r];
#pragma unroll
            for (int ni = 1; ni < 6; ++ni) {
                a = fmaxf(a, accx[mi][ni][r]);
                b = fmaxf(b, accy[mi][ni][r]);
            }
            mx[mi][r] = a; my_[mi][r] = b;
        }
#pragma unroll
    for (int off = 1; off < 16; off <<= 1)
#pragma unroll
        for (int mi = 0; mi < 2; ++mi)
#pragma unroll
            for (int r = 0; r < 4; ++r) {
                mx[mi][r]  = fmaxf(mx[mi][r],  __shfl_xor(mx[mi][r],  off));
                my_[mi][r] = fmaxf(my_[mi][r], __shfl_xor(my_[mi][r], off));
            }
    if (lm == 0)
#pragma unroll
        for (int mi = 0; mi < 2; ++mi)
#pragma unroll
            for (int r = 0; r < 4; ++r) {
                Smx[wave][mi * 16 + lq * 4 + r] = mx[mi][r];
                Smy[wave][mi * 16 + lq * 4 + r] = my_[mi][r];
            }
    __syncthreads();
#pragma unroll
    for (int mi = 0; mi < 2; ++mi)
#pragma unroll
        for (int r = 0; r < 4; ++r) {
            const int row = mi * 16 + lq * 4 + r;
            mx[mi][r]  = fmaxf(fmaxf(Smx[mg * 4 + 0][row], Smx[mg * 4 + 1][row]),
                               fmaxf(Smx[mg * 4 + 2][row], Smx[mg * 4 + 3][row]));
            my_[mi][r] = fmaxf(fmaxf(Smy[mg * 4 + 0][row], Smy[mg * 4 + 1][row]),
                               fmaxf(Smy[mg * 4 + 2][row], Smy[mg * 4 + 3][row]));
        }

    // row sum of exp (x and y)
    float sx[2][4], sy[2][4];
#pragma unroll
    for (int mi = 0; mi < 2; ++mi)
#pragma unroll
        for (int r = 0; r < 4; ++r) {
            float a = 0.f, b = 0.f;
#pragma unroll
            for (int ni = 0; ni < 6; ++ni) {
                a += __expf(accx[mi][ni][r] - mx[mi][r]);
                b += __expf(accy[mi][ni][r] - my_[mi][r]);
            }
            sx[mi][r] = a; sy[mi][r] = b;
        }
#pragma unroll
    for (int off = 1; off < 16; off <<= 1)
#pragma unroll
        for (int mi = 0; mi < 2; ++mi)
#pragma unroll
            for (int r = 0; r < 4; ++r) {
                sx[mi][r] += __shfl_xor(sx[mi][r], off);
                sy[mi][r] += __shfl_xor(sy[mi][r], off);
            }
    if (lm == 0)
#pragma unroll
        for (int mi = 0; mi < 2; ++mi)
#pragma unroll
            for (int r = 0; r < 4; ++r) {
                Ssx[wave][mi * 16 + lq * 4 + r] = sx[mi][r];
                Ssy[wave][mi * 16 + lq * 4 + r] = sy[mi][r];
            }
    __syncthreads();
#pragma unroll
    for (int mi = 0; mi < 2; ++mi)
#pragma unroll
        for (int r = 0; r < 4; ++r) {
            const int row = mi * 16 + lq * 4 + r;
            const float ssx = Ssx[mg * 4 + 0][row] + Ssx[mg * 4 + 1][row] +
                              Ssx[mg * 4 + 2][row] + Ssx[mg * 4 + 3][row];
            const float ssy = Ssy[mg * 4 + 0][row] + Ssy[mg * 4 + 1][row] +
                              Ssy[mg * 4 + 2][row] + Ssy[mg * 4 + 3][row];
            sx[mi][r] = mx[mi][r] + __logf(ssx);   // logp shift
            sy[mi][r] = 1.f / ssy;                 // q scale
        }

    // T partial + per-column sums over this wave's 32 rows
    float T = 0.f;
    float cL[6], cQ[6];
#pragma unroll
    for (int ni = 0; ni < 6; ++ni) { cL[ni] = 0.f; cQ[ni] = 0.f; }
#pragma unroll
    for (int mi = 0; mi < 2; ++mi)
#pragma unroll
        for (int r = 0; r < 4; ++r) {
            const float sh  = sx[mi][r];
            const float m   = my_[mi][r];
            const float inv = sy[mi][r];
#pragma unroll
            for (int ni = 0; ni < 6; ++ni) {
                const float lp = accx[mi][ni][r] - sh;
                const float qv = __expf(accy[mi][ni][r] - m) * inv;
                T += lp * qv;
                cL[ni] += lp;
                cQ[ni] += qv;
            }
        }
    // reduce col sums over lq (lanes lm, lm+16, lm+32, lm+48)
#pragma unroll
    for (int ni = 0; ni < 6; ++ni) {
        cL[ni] += __shfl_xor(cL[ni], 16); cL[ni] += __shfl_xor(cL[ni], 32);
        cQ[ni] += __shfl_xor(cQ[ni], 16); cQ[ni] += __shfl_xor(cQ[ni], 32);
    }
    if (lq == 0)
#pragma unroll
        for (int ni = 0; ni < 6; ++ni) {
            LcL[mg][wn + ni * 16 + lm] = cL[ni];
            LcQ[mg][wn + ni * 16 + lm] = cQ[ni];
        }
    // wave-reduce T
#pragma unroll
    for (int off = 32; off > 0; off >>= 1) T += __shfl_xor(T, off);
    if (lane == 0) sT[wave] = T;
    __syncthreads();

    // S_p = dot over 384 cols of (sum over both m-halves)
    float sp = 0.f;
    if (tid < HID) {
        const float L = LcL[0][tid] + LcL[1][tid];
        const float Q = LcQ[0][tid] + LcQ[1][tid];
        sp = L * Q;
    }
#pragma unroll
    for (int off = 32; off > 0; off >>= 1) sp += __shfl_xor(sp, off);
    if (lane == 0) sS[wave] = sp;
    __syncthreads();

    if (tid == 0) {
        float Tb = sT[0] + sT[1] + sT[2] + sT[3] + sT[4] + sT[5] + sT[6] + sT[7];
        float Sb = sS[0] + sS[1] + sS[2] + sS[3] + sS[4] + sS[5] + sS[6] + sS[7];
        atomicAdd(&scal[0], Tb);
        atomicAdd(&scal[1], Sb);
        __threadfence();
        int old = atomicAdd((int*)&scal[3], 1);
        if (old == (int)gridDim.x - 1) {
            float Tt = atomicAdd(&scal[0], 0.f);   // coherent read-back
            float St = atomicAdd(&scal[1], 0.f);
            out[0] = 63.f * Tt / (St - Tt);
        }
    }
}

extern "C" void kernel_launch(void* const* d_in, const int* in_sizes, int n_in,
                              void* d_out, int out_size, void* d_ws, size_t ws_size,
                              hipStream_t stream) {
    const float* x = (const float*)d_in[0];   // (64,3,224,224)
    const float* y = (const float*)d_in[1];   // (64,3,224,224)
    const float* W = (const float*)d_in[2];   // (384,768)
    const float* b = (const float*)d_in[3];   // (384,)
    float* out = (float*)d_out;

    float*    scal  = (float*)d_ws;                   // 16 f32: T,S,pad,cnt
    ushort_t* Wfrag = (ushort_t*)(scal + 16);         // 294912 bf16

    prep<<<144, 256, 0, stream>>>(W, Wfrag, scal);
    pe_all<<<196, 512, 0, stream>>>(x, y, Wfrag, b, scal, out);
}